// Round 17
// baseline (47.831 us; speedup 1.0000x reference)
//
#include <hip/hip_runtime.h>

// Problem constants
#define BB 8
#define CC 64
#define OO 64
#define HH 128
#define WWI 128
#define HWSZ (HH * WWI)     // 16384
#define KK 9                // 3x3 taps
#define II (KK * CC)        // 576

// patch / window geometry (main kernel)
#define PXW 16              // patch width  (x)
#define PYH 16              // patch height (y)
#define WNX 24              // window cols = PXW + 8
#define WNY 24              // window rows = PYH + 8
#define WROWS (WNX * WNY)   // 576 window rows, each 64 ch * 2B = 128B -> 72KB

typedef __attribute__((ext_vector_type(8))) _Float16 half8;
typedef __attribute__((ext_vector_type(2))) _Float16 h2;
typedef __attribute__((ext_vector_type(4))) float f32x4;
typedef __attribute__((ext_vector_type(4))) unsigned int uint4v;

__device__ __forceinline__ int iclamp(int v, int lo, int hi) {
    return v < lo ? lo : (v > hi ? hi : v);
}
__device__ __forceinline__ unsigned short f2h(float f) {
    union { _Float16 h; unsigned short s; } v;
    v.h = (_Float16)f;
    return v.s;
}
__device__ __forceinline__ h2 u2h(unsigned u) {
    union { unsigned u; h2 h; } v;
    v.u = u;
    return v.h;
}

// ---------- merged prep: blocks [0,2048) transpose x -> xt (fp16 NHWC);
// blocks [2048, 2192) build the fragment-ordered W layout.
__global__ __launch_bounds__(256) void prep_all(const float* __restrict__ x,
                                                unsigned short* __restrict__ xt,
                                                const float* __restrict__ w,
                                                unsigned short* __restrict__ waf) {
    const int blk = blockIdx.x;
    const int t = threadIdx.x;
    if (blk < 2048) {
        __shared__ float tile[64][65];
        const int b = blk & 7;
        const int p0 = (blk >> 3) * 64;
        const int a = t >> 6;   // 0..3
        const int q = t & 63;   // 0..63
        const float* xb = x + (size_t)b * CC * HWSZ + p0;
#pragma unroll
        for (int r = 0; r < 16; ++r) {
            int c = r * 4 + a;
            tile[c][q] = xb[(size_t)c * HWSZ + q];   // coalesced read
        }
        __syncthreads();
        unsigned short* xo = xt + ((size_t)b * HWSZ + p0) * CC;
#pragma unroll
        for (int r = 0; r < 16; ++r) {
            int pl = r * 4 + a;
            xo[(size_t)pl * CC + q] = f2h(tile[q][pl]);  // coalesced write
        }
    } else {
        // waf[slab][lane][j], slab = (k*2+kc)*4 + m, value =
        //   W.flat[o = m*16+(lane&15)][i = k*64 + kc*32 + (lane>>4)*8 + j]
        int tid = (blk - 2048) * 256 + t;
        if (tid < 72 * 512) {
            int slab = tid >> 9;           // 0..71
            int r = tid & 511;
            int l = r >> 3, j = r & 7;
            int m = slab & 3;
            int kc = (slab >> 2) & 1;
            int k = slab >> 3;
            int o = m * 16 + (l & 15);
            int i = k * 64 + kc * 32 + (l >> 4) * 8 + j;
            waf[tid] = f2h(w[(size_t)o * II + i]);
        }
    }
}

// ---------- main: 16x16 patch per block, window in LDS, 8 waves.
// r16 structure + WAVE DESYNC: stagger wave start ~128cyc apart so the CU's
// 16 resident waves occupy different pipeline phases (LDS-burst vs interp vs
// MFMA) instead of lockstep convoying through each phase together.
__global__ __launch_bounds__(512, 2) void deform_mfma15(
        const unsigned short* __restrict__ xt,   // [B][H][W][C] fp16
        const float* __restrict__ off,           // [B][2K][H][W]
        const unsigned short* __restrict__ waf,  // frag-ordered W, fp16
        const float* __restrict__ bias,          // [O]
        float* __restrict__ out) {               // [B][O][H][W]
    extern __shared__ unsigned short win[];      // WROWS * 64 shorts = 72KB

    const int blk = blockIdx.x;
    const int b = blk & 7;                 // XCD-ownership: image b on XCD b
    const int pidx = blk >> 3;             // 0..63
    const int y0 = (pidx >> 3) * PYH;      // 8 y-patches
    const int x0 = (pidx & 7) * PXW;       // 8 x-patches
    const int xleft = x0 - 4, ytop = y0 - 4;

    const int t = threadIdx.x;
    const int wave = t >> 6;               // 0..7
    const int lane = t & 63;
    const int fm = lane & 15;              // px-in-tile (B col)
    const int hi = lane >> 4;              // 0..3 (k-chunk)
    const int c0s = hi * 8;                // short offset, kc=0 chunk
    const int c1s = 32 + hi * 8;           // short offset, kc=1 chunk

    const unsigned short* xtb = xt + (size_t)b * HWSZ * CC;
    const float* offpx = off + (size_t)b * 2 * KK * HWSZ
                             + (size_t)(y0 + wave * 2) * WWI + x0 + fm;
    const float fxb = (float)(x0 + fm);
    const float fyb0 = (float)(y0 + wave * 2);
    const float fyb1 = fyb0 + 1.0f;

    // 3-slot offset ring (slot = tap%3); preload taps 0,1 before staging
    float ox[3][2], oy[3][2];
#pragma unroll
    for (int k = 0; k < 2; ++k) {
#pragma unroll
        for (int nt = 0; nt < 2; ++nt) {
            ox[k][nt] = offpx[(size_t)(2 * k + 0) * HWSZ + nt * WWI];
            oy[k][nt] = offpx[(size_t)(2 * k + 1) * HWSZ + nt * WWI];
        }
    }

    // A-fragment 3-deep ring (slot = tap%3); prefetch taps 0,1 BEFORE staging
    half8 afb[3][8];
#pragma unroll
    for (int k = 0; k < 2; ++k) {
        const unsigned short* wk = waf + (size_t)k * 8 * 512 + lane * 8;
#pragma unroll
        for (int q = 0; q < 8; ++q)
            afb[k][q] = *(const half8*)(wk + (size_t)q * 512);
    }

    // ---- stage window: rows (cy,cx) in [ytop,ytop+23] x [xleft,xleft+23] ----
    {
        const int tch = t & 7;             // 16B chunk within a row
        const int rb = t >> 3;             // 0..63
#pragma unroll
        for (int sw = 0; sw < 9; ++sw) {
            const int r = sw * 64 + rb;    // window row 0..575
            const int wy = r / WNX, wx = r - wy * WNX;
            const int cy = ytop + wy, cx = xleft + wx;
            if (((unsigned)cy < (unsigned)HH) && ((unsigned)cx < (unsigned)WWI)) {
                const uint4v v = *(const uint4v*)(xtb + (size_t)(cy * WWI + cx) * CC + tch * 8);
                *(uint4v*)&win[r * CC + ((tch ^ (r & 7)) << 3)] = v;  // swizzled
            }
        }
    }
    __syncthreads();

    // ---- WAVE DESYNC: skew = wave + 8*(block parity), ~128 cyc per step.
    // Spreads the CU's 16 resident waves across ~5 pipeline units so the
    // LDS / VALU / MFMA phases of different waves overlap instead of
    // convoying. (s_sleep immediate is constant; loop count is runtime.)
    {
        const int skew = wave + (((blk >> 3) & 1) << 3);   // 0..15
        for (int s = 0; s < skew; ++s) __builtin_amdgcn_s_sleep(2);
    }

    f32x4 acc[2][4];
#pragma unroll
    for (int nt = 0; nt < 2; ++nt)
#pragma unroll
        for (int m = 0; m < 4; ++m) acc[nt][m] = (f32x4)(0.0f);

    // pipeline state (all indices compile-time constants after macro expansion)
    uint4v cb[2][8];       // corner vectors, buffer = unit&1 (== nt)
    float  cw[2][4];       // folded bilinear weights
    bool   inwf[2];        // in-window flag
    int    gidx[2][4];     // global fallback row indices

#define LDSRD(r, kc) (*(const uint4v*)&win[(r) * CC + ((((hi) + ((kc) << 2)) ^ ((r) & 7)) << 3)])

    // ISSUE(u): coords + 8 ds_reads for unit u; on even u (k=u/2) also
    // prefetch offsets for tap k+2 and A-frags for tap k+1 (3 units ahead).
#define ISSUE(u) do {                                                           \
        if (((u) & 1) == 0) {                                                   \
            const int kpre_ = ((u) >> 1) + 2;                                   \
            if (kpre_ < KK) {                                                   \
                _Pragma("unroll")                                               \
                for (int nt = 0; nt < 2; ++nt) {                                \
                    ox[kpre_ % 3][nt] = offpx[(size_t)(2 * kpre_ + 0) * HWSZ + nt * WWI]; \
                    oy[kpre_ % 3][nt] = offpx[(size_t)(2 * kpre_ + 1) * HWSZ + nt * WWI]; \
                }                                                               \
            }                                                                   \
            const int kaf_ = ((u) >> 1) + 1;                                    \
            if (kaf_ >= 2 && kaf_ < KK) {                                       \
                const unsigned short* wk = waf + (size_t)kaf_ * 8 * 512 + lane * 8; \
                _Pragma("unroll")                                               \
                for (int q = 0; q < 8; ++q)                                     \
                    afb[kaf_ % 3][q] = *(const half8*)(wk + (size_t)q * 512);   \
            }                                                                   \
        }                                                                       \
        const float gx = ox[((u) >> 1) % 3][(u) & 1] + fxb;                     \
        const float gy = oy[((u) >> 1) % 3][(u) & 1] + (((u) & 1) ? fyb1 : fyb0); \
        const float fxf = floorf(gx), fyf = floorf(gy);                         \
        const float fx = gx - fxf, fy = gy - fyf;                               \
        const int ux0 = (int)fxf - 1, ux1 = (int)fxf;                           \
        const int uy0 = (int)fyf - 1, uy1 = (int)fyf;                           \
        const float vx0 = ((unsigned)ux0 < (unsigned)WWI) ? 1.0f : 0.0f;        \
        const float vx1 = ((unsigned)ux1 < (unsigned)WWI) ? 1.0f : 0.0f;        \
        const float vy0 = ((unsigned)uy0 < (unsigned)HH) ? 1.0f : 0.0f;         \
        const float vy1 = ((unsigned)uy1 < (unsigned)HH) ? 1.0f : 0.0f;         \
        cw[(u) & 1][0] = (1.0f - fy) * (1.0f - fx) * vy0 * vx0;                 \
        cw[(u) & 1][1] = (1.0f - fy) * fx          * vy0 * vx1;                 \
        cw[(u) & 1][2] = fy          * (1.0f - fx) * vy1 * vx0;                 \
        cw[(u) & 1][3] = fy          * fx          * vy1 * vx1;                 \
        const int cx0 = iclamp(ux0, 0, WWI - 1), cx1 = iclamp(ux1, 0, WWI - 1); \
        const int cy0 = iclamp(uy0, 0, HH - 1),  cy1 = iclamp(uy1, 0, HH - 1);  \
        inwf[(u) & 1] = (cx0 >= xleft) & (cx1 <= xleft + WNX - 1)               \
                      & (cy0 >= ytop) & (cy1 <= ytop + WNY - 1);                \
        gidx[(u) & 1][0] = cy0 * WWI + cx0;  gidx[(u) & 1][1] = cy0 * WWI + cx1;\
        gidx[(u) & 1][2] = cy1 * WWI + cx0;  gidx[(u) & 1][3] = cy1 * WWI + cx1;\
        const int wx0 = iclamp(cx0 - xleft, 0, WNX - 1);                        \
        const int wx1 = iclamp(cx1 - xleft, 0, WNX - 1);                        \
        const int wy0 = iclamp(cy0 - ytop, 0, WNY - 1);                         \
        const int wy1 = iclamp(cy1 - ytop, 0, WNY - 1);                         \
        const int r00 = wy0 * WNX + wx0, r01 = wy0 * WNX + wx1;                 \
        const int r10 = wy1 * WNX + wx0, r11 = wy1 * WNX + wx1;                 \
        cb[(u) & 1][0] = LDSRD(r00, 0);  cb[(u) & 1][1] = LDSRD(r00, 1);        \
        cb[(u) & 1][2] = LDSRD(r01, 0);  cb[(u) & 1][3] = LDSRD(r01, 1);        \
        cb[(u) & 1][4] = LDSRD(r10, 0);  cb[(u) & 1][5] = LDSRD(r10, 1);        \
        cb[(u) & 1][6] = LDSRD(r11, 0);  cb[(u) & 1][7] = LDSRD(r11, 1);        \
    } while (0)

    // PROC(u): pin corner regs (loads complete HERE), rare global fallback,
    // packed-fp16 interp, 8 MFMA into acc[nt] (setprio-wrapped).
#define PROC(u) do {                                                            \
        asm volatile("" : "+v"(cb[(u) & 1][0]), "+v"(cb[(u) & 1][1]),           \
                          "+v"(cb[(u) & 1][2]), "+v"(cb[(u) & 1][3]),           \
                          "+v"(cb[(u) & 1][4]), "+v"(cb[(u) & 1][5]),           \
                          "+v"(cb[(u) & 1][6]), "+v"(cb[(u) & 1][7]));          \
        uint4v A0 = cb[(u) & 1][0], A1 = cb[(u) & 1][1];                        \
        uint4v B0 = cb[(u) & 1][2], B1 = cb[(u) & 1][3];                        \
        uint4v C0 = cb[(u) & 1][4], C1 = cb[(u) & 1][5];                        \
        uint4v D0 = cb[(u) & 1][6], D1 = cb[(u) & 1][7];                        \
        if (!inwf[(u) & 1]) {                                                   \
            const unsigned short* g00 = xtb + (size_t)gidx[(u) & 1][0] * CC;    \
            const unsigned short* g01 = xtb + (size_t)gidx[(u) & 1][1] * CC;    \
            const unsigned short* g10 = xtb + (size_t)gidx[(u) & 1][2] * CC;    \
            const unsigned short* g11 = xtb + (size_t)gidx[(u) & 1][3] * CC;    \
            A0 = *(const uint4v*)(g00 + c0s);  A1 = *(const uint4v*)(g00 + c1s);\
            B0 = *(const uint4v*)(g01 + c0s);  B1 = *(const uint4v*)(g01 + c1s);\
            C0 = *(const uint4v*)(g10 + c0s);  C1 = *(const uint4v*)(g10 + c1s);\
            D0 = *(const uint4v*)(g11 + c0s);  D1 = *(const uint4v*)(g11 + c1s);\
        }                                                                       \
        const _Float16 hw00 = (_Float16)cw[(u) & 1][0];                         \
        const _Float16 hw01 = (_Float16)cw[(u) & 1][1];                         \
        const _Float16 hw10 = (_Float16)cw[(u) & 1][2];                         \
        const _Float16 hw11 = (_Float16)cw[(u) & 1][3];                         \
        const h2 w00v = {hw00, hw00}, w01v = {hw01, hw01};                      \
        const h2 w10v = {hw10, hw10}, w11v = {hw11, hw11};                      \
        half8 bf0, bf1;                                                         \
        h2* rp0 = (h2*)&bf0;                                                    \
        h2* rp1 = (h2*)&bf1;                                                    \
        _Pragma("unroll")                                                       \
        for (int i = 0; i < 4; ++i) {                                           \
            h2 r0 = u2h(A0[i]) * w00v;                                          \
            r0 += u2h(B0[i]) * w01v;                                            \
            r0 += u2h(C0[i]) * w10v;                                            \
            r0 += u2h(D0[i]) * w11v;                                            \
            rp0[i] = r0;                                                        \
            h2 r1 = u2h(A1[i]) * w00v;                                          \
            r1 += u2h(B1[i]) * w01v;                                            \
            r1 += u2h(C1[i]) * w10v;                                            \
            r1 += u2h(D1[i]) * w11v;                                            \
            rp1[i] = r1;                                                        \
        }                                                                       \
        __builtin_amdgcn_s_setprio(1);                                          \
        _Pragma("unroll")                                                       \
        for (int m = 0; m < 4; ++m)                                             \
            acc[(u) & 1][m] = __builtin_amdgcn_mfma_f32_16x16x32_f16(           \
                afb[((u) >> 1) % 3][m], bf0, acc[(u) & 1][m], 0, 0, 0);         \
        _Pragma("unroll")                                                       \
        for (int m = 0; m < 4; ++m)                                             \
            acc[(u) & 1][m] = __builtin_amdgcn_mfma_f32_16x16x32_f16(           \
                afb[((u) >> 1) % 3][4 + m], bf1, acc[(u) & 1][m], 0, 0, 0);     \
        __builtin_amdgcn_s_setprio(0);                                          \
    } while (0)

    // Schedule (r11-validated): I0 I1 P0 I2 P1 ... I17 P16 P17
    ISSUE(0);  ISSUE(1);
    PROC(0);   ISSUE(2);
    PROC(1);   ISSUE(3);
    PROC(2);   ISSUE(4);
    PROC(3);   ISSUE(5);
    PROC(4);   ISSUE(6);
    PROC(5);   ISSUE(7);
    PROC(6);   ISSUE(8);
    PROC(7);   ISSUE(9);
    PROC(8);   ISSUE(10);
    PROC(9);   ISSUE(11);
    PROC(10);  ISSUE(12);
    PROC(11);  ISSUE(13);
    PROC(12);  ISSUE(14);
    PROC(13);  ISSUE(15);
    PROC(14);  ISSUE(16);
    PROC(15);  ISSUE(17);
    PROC(16);
    PROC(17);

#undef ISSUE
#undef PROC
#undef LDSRD

    // epilogue: D col = fm (px), D row = hi*4 + j within m-tile -> o = m*16+hi*4+j
#pragma unroll
    for (int nt = 0; nt < 2; ++nt) {
        float* outb = out + (size_t)b * OO * HWSZ
                          + (size_t)(y0 + wave * 2 + nt) * WWI + x0 + fm;
#pragma unroll
        for (int m = 0; m < 4; ++m) {
            const int ob = m * 16 + hi * 4;
            const float4 bs = *(const float4*)(bias + ob);
#pragma unroll
            for (int j = 0; j < 4; ++j) {
                outb[(size_t)(ob + j) * HWSZ] = acc[nt][m][j] + ((const float*)&bs)[j];
            }
        }
    }
}

// ---------- fallback (round-1 fp32 path, used only if ws too small) ----------
__global__ __launch_bounds__(256) void deform_conv_fallback(
        const float* __restrict__ x, const float* __restrict__ off,
        const float* __restrict__ wmat, const float* __restrict__ bias,
        float* __restrict__ out) {
    const int b = blockIdx.y;
    const int p = blockIdx.x * 256 + threadIdx.x;
    const int wo = p & (WWI - 1);
    const int ho = p >> 7;
    const float* xb = x + (size_t)b * CC * HWSZ;
    const float* offb = off + (size_t)b * 2 * KK * HWSZ + p;
    float acc[OO];
#pragma unroll
    for (int o = 0; o < OO; ++o) acc[o] = 0.0f;
#pragma unroll 1
    for (int k = 0; k < KK; ++k) {
        const float gx = offb[(size_t)(2 * k + 0) * HWSZ] + (float)wo;
        const float gy = offb[(size_t)(2 * k + 1) * HWSZ] + (float)ho;
        const float fxf = floorf(gx), fyf = floorf(gy);
        const float fx = gx - fxf, fy = gy - fyf;
        const int ux0 = (int)fxf - 1, ux1 = (int)fxf;
        const int uy0 = (int)fyf - 1, uy1 = (int)fyf;
        const float vx0 = ((unsigned)ux0 < (unsigned)WWI) ? 1.0f : 0.0f;
        const float vx1 = ((unsigned)ux1 < (unsigned)WWI) ? 1.0f : 0.0f;
        const float vy0 = ((unsigned)uy0 < (unsigned)HH) ? 1.0f : 0.0f;
        const float vy1 = ((unsigned)uy1 < (unsigned)HH) ? 1.0f : 0.0f;
        const float w00 = (1.0f - fy) * (1.0f - fx) * vy0 * vx0;
        const float w01 = (1.0f - fy) * fx * vy0 * vx1;
        const float w10 = fy * (1.0f - fx) * vy1 * vx0;
        const float w11 = fy * fx * vy1 * vx1;
        const int cx0 = iclamp(ux0, 0, WWI - 1), cx1 = iclamp(ux1, 0, WWI - 1);
        const int cy0 = iclamp(uy0, 0, HH - 1), cy1 = iclamp(uy1, 0, HH - 1);
        const int i00 = cy0 * WWI + cx0, i01 = cy0 * WWI + cx1;
        const int i10 = cy1 * WWI + cx0, i11 = cy1 * WWI + cx1;
#pragma unroll 4
        for (int c = 0; c < CC; ++c) {
            const float* xc = xb + (size_t)c * HWSZ;
            const float v = w00 * xc[i00] + w01 * xc[i01] + w10 * xc[i10] + w11 * xc[i11];
            const float* wrow = wmat + (size_t)(k * CC + c);
#pragma unroll
            for (int o = 0; o < OO; ++o) acc[o] = fmaf(wrow[(size_t)o * II], v, acc[o]);
        }
    }
    float* outb = out + (size_t)b * OO * HWSZ + p;
#pragma unroll
    for (int o = 0; o < OO; ++o) outb[(size_t)o * HWSZ] = acc[o] + bias[o];
}

extern "C" void kernel_launch(void* const* d_in, const int* in_sizes, int n_in,
                              void* d_out, int out_size, void* d_ws, size_t ws_size,
                              hipStream_t stream) {
    const float* x    = (const float*)d_in[0];
    const float* off  = (const float*)d_in[1];
    const float* w    = (const float*)d_in[2];
    const float* bias = (const float*)d_in[3];
    float* out = (float*)d_out;

    const size_t xt_bytes  = (size_t)BB * HWSZ * CC * sizeof(unsigned short); // 16.78 MB
    const size_t waf_bytes = (size_t)72 * 512 * sizeof(unsigned short);       // 73728 B

    if (ws_size >= xt_bytes + waf_bytes) {
        unsigned short* xtp = (unsigned short*)d_ws;
        unsigned short* wfp = (unsigned short*)((char*)d_ws + xt_bytes);
        prep_all<<<dim3(2048 + 144), 256, 0, stream>>>(x, xtp, w, wfp);
        // 8 images x (8 y-patches * 8 x-patches) = 512 blocks, 72KB dyn LDS
        deform_mfma15<<<dim3(BB * (HH / PYH) * (WWI / PXW)), dim3(512),
                        WROWS * CC * sizeof(unsigned short), stream>>>(
            xtp, off, wfp, bias, out);
    } else {
        deform_conv_fallback<<<dim3(HWSZ / 256, BB), 256, 0, stream>>>(x, off, w, bias, out);
    }
}

// Round 18
// 45.762 us; speedup vs baseline: 1.0452x; 1.0452x over previous
//
#include <hip/hip_runtime.h>

// Problem constants
#define BB 8
#define CC 64
#define OO 64
#define HH 128
#define WWI 128
#define HWSZ (HH * WWI)     // 16384
#define KK 9                // 3x3 taps
#define II (KK * CC)        // 576

// patch / window geometry (main kernel)
#define PXW 16              // patch width  (x)
#define PYH 16              // patch height (y)
#define WNX 24              // window cols = PXW + 8
#define WNY 24              // window rows = PYH + 8
#define WROWS (WNX * WNY)   // 576 window rows, each 64 ch * 2B = 128B -> 72KB

typedef __attribute__((ext_vector_type(8))) _Float16 half8;
typedef __attribute__((ext_vector_type(2))) _Float16 h2;
typedef __attribute__((ext_vector_type(4))) float f32x4;
typedef __attribute__((ext_vector_type(4))) unsigned int uint4v;

__device__ __forceinline__ int iclamp(int v, int lo, int hi) {
    return v < lo ? lo : (v > hi ? hi : v);
}
__device__ __forceinline__ unsigned short f2h(float f) {
    union { _Float16 h; unsigned short s; } v;
    v.h = (_Float16)f;
    return v.s;
}
__device__ __forceinline__ h2 u2h(unsigned u) {
    union { unsigned u; h2 h; } v;
    v.u = u;
    return v.h;
}

// ---------- merged prep: blocks [0,2048) transpose x -> xt (fp16 NHWC);
// blocks [2048, 2192) build the fragment-ordered W layout.
__global__ __launch_bounds__(256) void prep_all(const float* __restrict__ x,
                                                unsigned short* __restrict__ xt,
                                                const float* __restrict__ w,
                                                unsigned short* __restrict__ waf) {
    const int blk = blockIdx.x;
    const int t = threadIdx.x;
    if (blk < 2048) {
        __shared__ float tile[64][65];
        const int b = blk & 7;
        const int p0 = (blk >> 3) * 64;
        const int a = t >> 6;   // 0..3
        const int q = t & 63;   // 0..63
        const float* xb = x + (size_t)b * CC * HWSZ + p0;
#pragma unroll
        for (int r = 0; r < 16; ++r) {
            int c = r * 4 + a;
            tile[c][q] = xb[(size_t)c * HWSZ + q];   // coalesced read
        }
        __syncthreads();
        unsigned short* xo = xt + ((size_t)b * HWSZ + p0) * CC;
#pragma unroll
        for (int r = 0; r < 16; ++r) {
            int pl = r * 4 + a;
            xo[(size_t)pl * CC + q] = f2h(tile[q][pl]);  // coalesced write
        }
    } else {
        // waf[slab][lane][j], slab = (k*2+kc)*4 + m, value =
        //   W.flat[o = m*16+(lane&15)][i = k*64 + kc*32 + (lane>>4)*8 + j]
        int tid = (blk - 2048) * 256 + t;
        if (tid < 72 * 512) {
            int slab = tid >> 9;           // 0..71
            int r = tid & 511;
            int l = r >> 3, j = r & 7;
            int m = slab & 3;
            int kc = (slab >> 2) & 1;
            int k = slab >> 3;
            int o = m * 16 + (l & 15);
            int i = k * 64 + kc * 32 + (l >> 4) * 8 + j;
            waf[tid] = f2h(w[(size_t)o * II + i]);
        }
    }
}

// ---------- main: 16x16 patch per block, window in LDS, 8 waves.
// Best-known configuration (r11/r15/r16-validated): depth-2 (tap,nt)-unit
// register pipeline, asm-pinned ds_reads, packed-fp16 interp, setprio MFMA.
__global__ __launch_bounds__(512, 2) void deform_mfma16(
        const unsigned short* __restrict__ xt,   // [B][H][W][C] fp16
        const float* __restrict__ off,           // [B][2K][H][W]
        const unsigned short* __restrict__ waf,  // frag-ordered W, fp16
        const float* __restrict__ bias,          // [O]
        float* __restrict__ out) {               // [B][O][H][W]
    extern __shared__ unsigned short win[];      // WROWS * 64 shorts = 72KB

    const int blk = blockIdx.x;
    const int b = blk & 7;                 // XCD-ownership: image b on XCD b
    const int pidx = blk >> 3;             // 0..63
    const int y0 = (pidx >> 3) * PYH;      // 8 y-patches
    const int x0 = (pidx & 7) * PXW;       // 8 x-patches
    const int xleft = x0 - 4, ytop = y0 - 4;

    const int t = threadIdx.x;
    const int wave = t >> 6;               // 0..7
    const int lane = t & 63;
    const int fm = lane & 15;              // px-in-tile (B col)
    const int hi = lane >> 4;              // 0..3 (k-chunk)
    const int c0s = hi * 8;                // short offset, kc=0 chunk
    const int c1s = 32 + hi * 8;           // short offset, kc=1 chunk

    const unsigned short* xtb = xt + (size_t)b * HWSZ * CC;
    const float* offpx = off + (size_t)b * 2 * KK * HWSZ
                             + (size_t)(y0 + wave * 2) * WWI + x0 + fm;

    // 3-slot offset ring (slot = tap%3); preload taps 0,1 before staging
    float ox[3][2], oy[3][2];
#pragma unroll
    for (int k = 0; k < 2; ++k) {
#pragma unroll
        for (int nt = 0; nt < 2; ++nt) {
            ox[k][nt] = offpx[(size_t)(2 * k + 0) * HWSZ + nt * WWI];
            oy[k][nt] = offpx[(size_t)(2 * k + 1) * HWSZ + nt * WWI];
        }
    }

    // ---- stage window: rows (cy,cx) in [ytop,ytop+23] x [xleft,xleft+23] ----
    {
        const int tch = t & 7;             // 16B chunk within a row
        const int rb = t >> 3;             // 0..63
#pragma unroll
        for (int sw = 0; sw < 9; ++sw) {
            const int r = sw * 64 + rb;    // window row 0..575
            const int wy = r / WNX, wx = r - wy * WNX;
            const int cy = ytop + wy, cx = xleft + wx;
            if (((unsigned)cy < (unsigned)HH) && ((unsigned)cx < (unsigned)WWI)) {
                const uint4v v = *(const uint4v*)(xtb + (size_t)(cy * WWI + cx) * CC + tch * 8);
                *(uint4v*)&win[r * CC + ((tch ^ (r & 7)) << 3)] = v;  // swizzled
            }
        }
    }
    __syncthreads();

    f32x4 acc[2][4];
#pragma unroll
    for (int nt = 0; nt < 2; ++nt)
#pragma unroll
        for (int m = 0; m < 4; ++m) acc[nt][m] = (f32x4)(0.0f);

    // pipeline state (all indices compile-time constants after macro expansion)
    uint4v cb[2][8];       // corner vectors, buffer = unit&1 (== nt)
    float  cw[2][4];       // folded bilinear weights
    bool   inwf[2];        // in-window flag
    int    gidx[2][4];     // global fallback row indices
    half8  afb[2][8];      // A-fragments, buffer = tap&1

#define LDSRD(r, kc) (*(const uint4v*)&win[(r) * CC + ((((hi) + ((kc) << 2)) ^ ((r) & 7)) << 3)])

    // ISSUE(u): coords + 8 ds_reads for unit u; on nt==0 also prefetch
    // offsets for tap k+2 (ring) and A-frags for tap k.
#define ISSUE(u) do {                                                           \
        if ((((u) & 1) == 0) && (((u) >> 1) + 2 < KK)) {                        \
            _Pragma("unroll")                                                   \
            for (int nt = 0; nt < 2; ++nt) {                                    \
                ox[(((u) >> 1) + 2) % 3][nt] =                                  \
                    offpx[(size_t)(2 * (((u) >> 1) + 2) + 0) * HWSZ + nt * WWI];\
                oy[(((u) >> 1) + 2) % 3][nt] =                                  \
                    offpx[(size_t)(2 * (((u) >> 1) + 2) + 1) * HWSZ + nt * WWI];\
            }                                                                   \
        }                                                                       \
        if (((u) & 1) == 0) {                                                   \
            const unsigned short* wk = waf + (size_t)((u) >> 1) * 8 * 512 + lane * 8; \
            _Pragma("unroll")                                                   \
            for (int q = 0; q < 8; ++q)                                         \
                afb[((u) >> 1) & 1][q] = *(const half8*)(wk + (size_t)q * 512); \
        }                                                                       \
        const float gx = ox[((u) >> 1) % 3][(u) & 1] + (float)(x0 + fm);        \
        const float gy = oy[((u) >> 1) % 3][(u) & 1] + (float)(y0 + wave * 2 + ((u) & 1)); \
        const float fxf = floorf(gx), fyf = floorf(gy);                         \
        const float fx = gx - fxf, fy = gy - fyf;                               \
        const int ux0 = (int)fxf - 1, ux1 = (int)fxf;                           \
        const int uy0 = (int)fyf - 1, uy1 = (int)fyf;                           \
        const float vx0 = ((unsigned)ux0 < (unsigned)WWI) ? 1.0f : 0.0f;        \
        const float vx1 = ((unsigned)ux1 < (unsigned)WWI) ? 1.0f : 0.0f;        \
        const float vy0 = ((unsigned)uy0 < (unsigned)HH) ? 1.0f : 0.0f;         \
        const float vy1 = ((unsigned)uy1 < (unsigned)HH) ? 1.0f : 0.0f;         \
        cw[(u) & 1][0] = (1.0f - fy) * (1.0f - fx) * vy0 * vx0;                 \
        cw[(u) & 1][1] = (1.0f - fy) * fx          * vy0 * vx1;                 \
        cw[(u) & 1][2] = fy          * (1.0f - fx) * vy1 * vx0;                 \
        cw[(u) & 1][3] = fy          * fx          * vy1 * vx1;                 \
        const int cx0 = iclamp(ux0, 0, WWI - 1), cx1 = iclamp(ux1, 0, WWI - 1); \
        const int cy0 = iclamp(uy0, 0, HH - 1),  cy1 = iclamp(uy1, 0, HH - 1);  \
        inwf[(u) & 1] = (cx0 >= xleft) & (cx1 <= xleft + WNX - 1)               \
                      & (cy0 >= ytop) & (cy1 <= ytop + WNY - 1);                \
        gidx[(u) & 1][0] = cy0 * WWI + cx0;  gidx[(u) & 1][1] = cy0 * WWI + cx1;\
        gidx[(u) & 1][2] = cy1 * WWI + cx0;  gidx[(u) & 1][3] = cy1 * WWI + cx1;\
        const int wx0 = iclamp(cx0 - xleft, 0, WNX - 1);                        \
        const int wx1 = iclamp(cx1 - xleft, 0, WNX - 1);                        \
        const int wy0 = iclamp(cy0 - ytop, 0, WNY - 1);                         \
        const int wy1 = iclamp(cy1 - ytop, 0, WNY - 1);                         \
        const int r00 = wy0 * WNX + wx0, r01 = wy0 * WNX + wx1;                 \
        const int r10 = wy1 * WNX + wx0, r11 = wy1 * WNX + wx1;                 \
        cb[(u) & 1][0] = LDSRD(r00, 0);  cb[(u) & 1][1] = LDSRD(r00, 1);        \
        cb[(u) & 1][2] = LDSRD(r01, 0);  cb[(u) & 1][3] = LDSRD(r01, 1);        \
        cb[(u) & 1][4] = LDSRD(r10, 0);  cb[(u) & 1][5] = LDSRD(r10, 1);        \
        cb[(u) & 1][6] = LDSRD(r11, 0);  cb[(u) & 1][7] = LDSRD(r11, 1);        \
    } while (0)

    // PROC(u): pin corner regs (loads complete HERE), rare global fallback,
    // packed-fp16 interp, 8 MFMA into acc[nt] (setprio-wrapped).
#define PROC(u) do {                                                            \
        asm volatile("" : "+v"(cb[(u) & 1][0]), "+v"(cb[(u) & 1][1]),           \
                          "+v"(cb[(u) & 1][2]), "+v"(cb[(u) & 1][3]),           \
                          "+v"(cb[(u) & 1][4]), "+v"(cb[(u) & 1][5]),           \
                          "+v"(cb[(u) & 1][6]), "+v"(cb[(u) & 1][7]));          \
        uint4v A0 = cb[(u) & 1][0], A1 = cb[(u) & 1][1];                        \
        uint4v B0 = cb[(u) & 1][2], B1 = cb[(u) & 1][3];                        \
        uint4v C0 = cb[(u) & 1][4], C1 = cb[(u) & 1][5];                        \
        uint4v D0 = cb[(u) & 1][6], D1 = cb[(u) & 1][7];                        \
        if (!inwf[(u) & 1]) {                                                   \
            const unsigned short* g00 = xtb + (size_t)gidx[(u) & 1][0] * CC;    \
            const unsigned short* g01 = xtb + (size_t)gidx[(u) & 1][1] * CC;    \
            const unsigned short* g10 = xtb + (size_t)gidx[(u) & 1][2] * CC;    \
            const unsigned short* g11 = xtb + (size_t)gidx[(u) & 1][3] * CC;    \
            A0 = *(const uint4v*)(g00 + c0s);  A1 = *(const uint4v*)(g00 + c1s);\
            B0 = *(const uint4v*)(g01 + c0s);  B1 = *(const uint4v*)(g01 + c1s);\
            C0 = *(const uint4v*)(g10 + c0s);  C1 = *(const uint4v*)(g10 + c1s);\
            D0 = *(const uint4v*)(g11 + c0s);  D1 = *(const uint4v*)(g11 + c1s);\
        }                                                                       \
        const _Float16 hw00 = (_Float16)cw[(u) & 1][0];                         \
        const _Float16 hw01 = (_Float16)cw[(u) & 1][1];                         \
        const _Float16 hw10 = (_Float16)cw[(u) & 1][2];                         \
        const _Float16 hw11 = (_Float16)cw[(u) & 1][3];                         \
        const h2 w00v = {hw00, hw00}, w01v = {hw01, hw01};                      \
        const h2 w10v = {hw10, hw10}, w11v = {hw11, hw11};                      \
        half8 bf0, bf1;                                                         \
        h2* rp0 = (h2*)&bf0;                                                    \
        h2* rp1 = (h2*)&bf1;                                                    \
        _Pragma("unroll")                                                       \
        for (int i = 0; i < 4; ++i) {                                           \
            h2 r0 = u2h(A0[i]) * w00v;                                          \
            r0 += u2h(B0[i]) * w01v;                                            \
            r0 += u2h(C0[i]) * w10v;                                            \
            r0 += u2h(D0[i]) * w11v;                                            \
            rp0[i] = r0;                                                        \
            h2 r1 = u2h(A1[i]) * w00v;                                          \
            r1 += u2h(B1[i]) * w01v;                                            \
            r1 += u2h(C1[i]) * w10v;                                            \
            r1 += u2h(D1[i]) * w11v;                                            \
            rp1[i] = r1;                                                        \
        }                                                                       \
        __builtin_amdgcn_s_setprio(1);                                          \
        _Pragma("unroll")                                                       \
        for (int m = 0; m < 4; ++m)                                             \
            acc[(u) & 1][m] = __builtin_amdgcn_mfma_f32_16x16x32_f16(           \
                afb[((u) >> 1) & 1][m], bf0, acc[(u) & 1][m], 0, 0, 0);         \
        _Pragma("unroll")                                                       \
        for (int m = 0; m < 4; ++m)                                             \
            acc[(u) & 1][m] = __builtin_amdgcn_mfma_f32_16x16x32_f16(           \
                afb[((u) >> 1) & 1][4 + m], bf1, acc[(u) & 1][m], 0, 0, 0);     \
        __builtin_amdgcn_s_setprio(0);                                          \
    } while (0)

    // Schedule (r11-validated): I0 I1 P0 I2 P1 ... I17 P16 P17
    ISSUE(0);  ISSUE(1);
    PROC(0);   ISSUE(2);
    PROC(1);   ISSUE(3);
    PROC(2);   ISSUE(4);
    PROC(3);   ISSUE(5);
    PROC(4);   ISSUE(6);
    PROC(5);   ISSUE(7);
    PROC(6);   ISSUE(8);
    PROC(7);   ISSUE(9);
    PROC(8);   ISSUE(10);
    PROC(9);   ISSUE(11);
    PROC(10);  ISSUE(12);
    PROC(11);  ISSUE(13);
    PROC(12);  ISSUE(14);
    PROC(13);  ISSUE(15);
    PROC(14);  ISSUE(16);
    PROC(15);  ISSUE(17);
    PROC(16);
    PROC(17);

#undef ISSUE
#undef PROC
#undef LDSRD

    // epilogue: D col = fm (px), D row = hi*4 + j within m-tile -> o = m*16+hi*4+j
#pragma unroll
    for (int nt = 0; nt < 2; ++nt) {
        float* outb = out + (size_t)b * OO * HWSZ
                          + (size_t)(y0 + wave * 2 + nt) * WWI + x0 + fm;
#pragma unroll
        for (int m = 0; m < 4; ++m) {
            const int ob = m * 16 + hi * 4;
            const float4 bs = *(const float4*)(bias + ob);
#pragma unroll
            for (int j = 0; j < 4; ++j) {
                outb[(size_t)(ob + j) * HWSZ] = acc[nt][m][j] + ((const float*)&bs)[j];
            }
        }
    }
}

// ---------- fallback (round-1 fp32 path, used only if ws too small) ----------
__global__ __launch_bounds__(256) void deform_conv_fallback(
        const float* __restrict__ x, const float* __restrict__ off,
        const float* __restrict__ wmat, const float* __restrict__ bias,
        float* __restrict__ out) {
    const int b = blockIdx.y;
    const int p = blockIdx.x * 256 + threadIdx.x;
    const int wo = p & (WWI - 1);
    const int ho = p >> 7;
    const float* xb = x + (size_t)b * CC * HWSZ;
    const float* offb = off + (size_t)b * 2 * KK * HWSZ + p;
    float acc[OO];
#pragma unroll
    for (int o = 0; o < OO; ++o) acc[o] = 0.0f;
#pragma unroll 1
    for (int k = 0; k < KK; ++k) {
        const float gx = offb[(size_t)(2 * k + 0) * HWSZ] + (float)wo;
        const float gy = offb[(size_t)(2 * k + 1) * HWSZ] + (float)ho;
        const float fxf = floorf(gx), fyf = floorf(gy);
        const float fx = gx - fxf, fy = gy - fyf;
        const int ux0 = (int)fxf - 1, ux1 = (int)fxf;
        const int uy0 = (int)fyf - 1, uy1 = (int)fyf;
        const float vx0 = ((unsigned)ux0 < (unsigned)WWI) ? 1.0f : 0.0f;
        const float vx1 = ((unsigned)ux1 < (unsigned)WWI) ? 1.0f : 0.0f;
        const float vy0 = ((unsigned)uy0 < (unsigned)HH) ? 1.0f : 0.0f;
        const float vy1 = ((unsigned)uy1 < (unsigned)HH) ? 1.0f : 0.0f;
        const float w00 = (1.0f - fy) * (1.0f - fx) * vy0 * vx0;
        const float w01 = (1.0f - fy) * fx * vy0 * vx1;
        const float w10 = fy * (1.0f - fx) * vy1 * vx0;
        const float w11 = fy * fx * vy1 * vx1;
        const int cx0 = iclamp(ux0, 0, WWI - 1), cx1 = iclamp(ux1, 0, WWI - 1);
        const int cy0 = iclamp(uy0, 0, HH - 1), cy1 = iclamp(uy1, 0, HH - 1);
        const int i00 = cy0 * WWI + cx0, i01 = cy0 * WWI + cx1;
        const int i10 = cy1 * WWI + cx0, i11 = cy1 * WWI + cx1;
#pragma unroll 4
        for (int c = 0; c < CC; ++c) {
            const float* xc = xb + (size_t)c * HWSZ;
            const float v = w00 * xc[i00] + w01 * xc[i01] + w10 * xc[i10] + w11 * xc[i11];
            const float* wrow = wmat + (size_t)(k * CC + c);
#pragma unroll
            for (int o = 0; o < OO; ++o) acc[o] = fmaf(wrow[(size_t)o * II], v, acc[o]);
        }
    }
    float* outb = out + (size_t)b * OO * HWSZ + p;
#pragma unroll
    for (int o = 0; o < OO; ++o) outb[(size_t)o * HWSZ] = acc[o] + bias[o];
}

extern "C" void kernel_launch(void* const* d_in, const int* in_sizes, int n_in,
                              void* d_out, int out_size, void* d_ws, size_t ws_size,
                              hipStream_t stream) {
    const float* x    = (const float*)d_in[0];
    const float* off  = (const float*)d_in[1];
    const float* w    = (const float*)d_in[2];
    const float* bias = (const float*)d_in[3];
    float* out = (float*)d_out;

    const size_t xt_bytes  = (size_t)BB * HWSZ * CC * sizeof(unsigned short); // 16.78 MB
    const size_t waf_bytes = (size_t)72 * 512 * sizeof(unsigned short);       // 73728 B

    if (ws_size >= xt_bytes + waf_bytes) {
        unsigned short* xtp = (unsigned short*)d_ws;
        unsigned short* wfp = (unsigned short*)((char*)d_ws + xt_bytes);
        prep_all<<<dim3(2048 + 144), 256, 0, stream>>>(x, xtp, w, wfp);
        // 8 images x (8 y-patches * 8 x-patches) = 512 blocks, 72KB dyn LDS
        deform_mfma16<<<dim3(BB * (HH / PYH) * (WWI / PXW)), dim3(512),
                        WROWS * CC * sizeof(unsigned short), stream>>>(
            xtp, off, wfp, bias, out);
    } else {
        deform_conv_fallback<<<dim3(HWSZ / 256, BB), 256, 0, stream>>>(x, off, w, bias, out);
    }
}